// Round 2
// baseline (918.212 us; speedup 1.0000x reference)
//
#include <hip/hip_runtime.h>
#include <hip/hip_bf16.h>

typedef __attribute__((ext_vector_type(4))) float f32x4;
typedef __attribute__((ext_vector_type(4))) int   i32x4;
typedef __attribute__((ext_vector_type(8))) short s16x8;
typedef __attribute__((ext_vector_type(4))) unsigned short u16x4;

#define T_ 512
#define B_ 8
#define H_ 128
#define V_ 32000
#define M_ 4096   // T_*B_

// round-to-nearest-even f32 -> bf16
__device__ __forceinline__ unsigned short f2b(float f) {
  unsigned int u = __float_as_uint(f);
  u = (u + 0x7FFFu + ((u >> 16) & 1u)) >> 16;
  return (unsigned short)u;
}

__device__ __forceinline__ float tanh_fast(float x) {
  float e = __expf(2.f * x);
  return 1.f - 2.f * __builtin_amdgcn_rcpf(e + 1.f);
}

__device__ __forceinline__ float hsum4(f32x4 v) {
  return (v.x + v.y) + (v.z + v.w);
}

// ---------------- fc_W f32 -> bf16 ----------------
__global__ __launch_bounds__(256) void convert_w_kernel(const float* __restrict__ src,
                                                        unsigned short* __restrict__ dst, int n4) {
  int idx = blockIdx.x * 256 + threadIdx.x;
  int stride = gridDim.x * 256;
  for (int c = idx; c < n4; c += stride) {
    f32x4 v = ((const f32x4*)src)[c];
    u16x4 o;
    o.x = f2b(v.x); o.y = f2b(v.y); o.z = f2b(v.z); o.w = f2b(v.w);
    ((u16x4*)dst)[c] = o;
  }
}

// ---------------- pre0 = emb[x] @ W_ih0^T + b_ih0 + b_hh0 ----------------
__global__ __launch_bounds__(128) void pre_kernel(const float* __restrict__ emb,
                                                  const int* __restrict__ x,
                                                  const float* __restrict__ W,
                                                  const float* __restrict__ b1,
                                                  const float* __restrict__ b2,
                                                  float* __restrict__ out) {
  const int tid = threadIdx.x;
  __shared__ alignas(16) float lds_in[H_];
  f32x4 w[32];
#pragma unroll
  for (int r = 0; r < 32; ++r) w[r] = *(const f32x4*)(W + tid * H_ + 4 * r);
  const float bsum = b1[tid] + b2[tid];
  const int m0 = blockIdx.x * 16;

  auto src_row = [&](int m) -> const float* {
    int t = m >> 3, b = m & 7;
    int tok = x[(b << 9) + t];          // x is [B,T]
    return emb + (size_t)tok * H_;
  };

  float stage = src_row(m0)[tid];
  for (int rr = 0; rr < 16; ++rr) {
    const int m = m0 + rr;
    lds_in[tid] = stage;
    __syncthreads();
    if (rr + 1 < 16) stage = src_row(m0 + rr + 1)[tid];
    f32x4 acc4 = {0.f, 0.f, 0.f, 0.f};
#pragma unroll
    for (int r = 0; r < 32; ++r) {
      f32x4 hv = *(const f32x4*)(lds_in + 4 * r);
      acc4 = __builtin_elementwise_fma(hv, w[r], acc4);
    }
    out[m * H_ + tid] = hsum4(acc4) + bsum;
    __syncthreads();
  }
}

// ---------------- fused dual-layer scan ----------------
// One block per batch, 3 waves (192 threads), one barrier per region, 514 regions.
// Wave 0/1 (A-role, lane owns row i = w*64+lane):
//   h0[s]   = tanh(pre0[s] + W_hh0[i]·h0[s-1])          (s in [0,511])
//   p_ih    = W_ih1[i]·h0[s-1] + b_ih1[i] + b_hh1[i]    -> part[(s-1)&1][i]  (s in [1,512])
//   (same LDS broadcast chunk feeds BOTH dots: 2 FMAs per read)
// Wave 2 (B1-role, lane owns rows lane and lane+64):
//   finalize h1[s-2] = tanh(p_hh_regs + part[(s-2)&1])  (s in [2,513]); write LDS + global bf16
//   then p_hh_regs = W_hh1·h1[s-2]  (same-wave write->broadcast-read, in-order LDS pipe)
__global__ __launch_bounds__(192, 1) void fused_scan(
    const float* __restrict__ pre0,
    const float* __restrict__ W_hh0,
    const float* __restrict__ W_ih1,
    const float* __restrict__ W_hh1,
    const float* __restrict__ b_ih1,
    const float* __restrict__ b_hh1,
    unsigned short* __restrict__ h1b) {
  const int b = blockIdx.x;
  const int tid = threadIdx.x;
  const int w = tid >> 6, lane = tid & 63;

  __shared__ alignas(16) float h0_lds[2][H_];
  __shared__ alignas(16) float h1_lds[H_];
  __shared__ float part[2][H_];

  if (tid < H_) { h0_lds[0][tid] = 0.f; h0_lds[1][tid] = 0.f; }

  // per-thread weights: wA = 1st matrix row, wB = 2nd matrix row (64 x f32x4 = 256 VGPR)
  f32x4 wA[32], wB[32];
  float bsum = 0.f;
  const int iA = ((w & 1) << 6) + lane;   // A-role row (w<2); also reused as generic index
  if (w < 2) {
#pragma unroll
    for (int r = 0; r < 32; ++r) wA[r] = *(const f32x4*)(W_hh0 + iA * H_ + 4 * r);
#pragma unroll
    for (int r = 0; r < 32; ++r) wB[r] = *(const f32x4*)(W_ih1 + iA * H_ + 4 * r);
    bsum = b_ih1[iA] + b_hh1[iA];
  } else {
#pragma unroll
    for (int r = 0; r < 32; ++r) wA[r] = *(const f32x4*)(W_hh1 + lane * H_ + 4 * r);
#pragma unroll
    for (int r = 0; r < 32; ++r) wB[r] = *(const f32x4*)(W_hh1 + (lane + 64) * H_ + 4 * r);
  }

  float phh0 = 0.f, phh1 = 0.f;   // B1 carried partials
  float pre_c = 0.f;
  if (w < 2) pre_c = pre0[(b << 7) + iA];   // s = 0 term
  __syncthreads();

  for (int s = 0; s < T_ + 2; ++s) {
    if (w < 2) {
      float pre_n = 0.f;
      if (s + 1 < T_) pre_n = pre0[(((s + 1) * B_ + b) << 7) + iA];
      const float* hb = h0_lds[(s + 1) & 1];   // h0[s-1]
      f32x4 a0 = {0.f, 0.f, 0.f, 0.f}, a1 = {0.f, 0.f, 0.f, 0.f};
#pragma unroll
      for (int r = 0; r < 32; ++r) {
        f32x4 hv = *(const f32x4*)(hb + 4 * r);
        a0 = __builtin_elementwise_fma(hv, wA[r], a0);
        a1 = __builtin_elementwise_fma(hv, wB[r], a1);
      }
      if (s < T_) h0_lds[s & 1][iA] = tanh_fast(pre_c + hsum4(a0));
      if (s >= 1 && s <= T_) part[(s - 1) & 1][iA] = hsum4(a1) + bsum;
      pre_c = pre_n;
    } else if (s >= 2) {
      // finalize h1[s-2]
      float h1a = tanh_fast(phh0 + part[s & 1][lane]);
      float h1c = tanh_fast(phh1 + part[s & 1][lane + 64]);
      h1_lds[lane] = h1a;
      h1_lds[lane + 64] = h1c;
      const int t = s - 2;
      h1b[((t * B_ + b) << 7) + lane]      = f2b(h1a);
      h1b[((t * B_ + b) << 7) + lane + 64] = f2b(h1c);
      // p_hh for h1[s-1] from just-written h1[s-2] (same-wave, in-order LDS)
      f32x4 a0 = {0.f, 0.f, 0.f, 0.f}, a1 = {0.f, 0.f, 0.f, 0.f};
#pragma unroll
      for (int r = 0; r < 32; ++r) {
        f32x4 hv = *(const f32x4*)(h1_lds + 4 * r);
        a0 = __builtin_elementwise_fma(hv, wA[r], a0);
        a1 = __builtin_elementwise_fma(hv, wB[r], a1);
      }
      phh0 = hsum4(a0);
      phh1 = hsum4(a1);
    }
    __syncthreads();
  }
}

// ---------------- logits = h1 @ fc_W^T + fc_b  (bf16 MFMA, v2) ----------------
// A = fcWb tile [128 v][128 k] (LDS, swizzled); B = h1b fragments direct from global (L2-hot).
// D: row = v (lg*4+r -> v-consecutive => f32x4 stores), col = m (l15).
__device__ __forceinline__ int swz(int row, int cc) {
  return row * 256 + ((cc ^ (row & 7)) << 4);
}

__global__ __launch_bounds__(256) void final_gemm2(const unsigned short* __restrict__ fcWb,
                                                   const unsigned short* __restrict__ h1b,
                                                   const float* __restrict__ bias,
                                                   float* __restrict__ out) {
  __shared__ alignas(16) char smem[32768];
  const int tid = threadIdx.x;
  const int bid = blockIdx.x;
  const int mt = bid & 31, nt = bid >> 5;   // consecutive bids share the fcW tile
  const int m0 = mt << 7, v0 = nt << 7;
  const int lane = tid & 63, wv = tid >> 6;
  const int wm = wv & 1, wq = wv >> 1;      // wave m-half, v-half

  // stage fcW tile (32KB) with swizzle
  const char* gW = (const char*)fcWb + (size_t)v0 * 256;
#pragma unroll
  for (int it = 0; it < 8; ++it) {
    int c = it * 256 + tid;
    i32x4 vw = *(const i32x4*)(gW + c * 16);
    *(i32x4*)(smem + swz(c >> 4, c & 15)) = vw;
  }
  __syncthreads();

  const int l15 = lane & 15, lg = lane >> 4;
  f32x4 acc[4][4] = {};   // [vf][mf]
#pragma unroll
  for (int kk = 0; kk < 4; ++kk) {
    const int cc = kk * 4 + lg;
    s16x8 a[4], bfr[4];
#pragma unroll
    for (int vf = 0; vf < 4; ++vf) {
      int row = wq * 64 + vf * 16 + l15;
      a[vf] = *(const s16x8*)(smem + swz(row, cc));
    }
#pragma unroll
    for (int mf = 0; mf < 4; ++mf) {
      int mr = m0 + wm * 64 + mf * 16 + l15;
      bfr[mf] = *(const s16x8*)(h1b + mr * H_ + kk * 32 + lg * 8);
    }
#pragma unroll
    for (int vf = 0; vf < 4; ++vf)
#pragma unroll
      for (int mf = 0; mf < 4; ++mf)
        acc[vf][mf] = __builtin_amdgcn_mfma_f32_16x16x32_bf16(a[vf], bfr[mf], acc[vf][mf], 0, 0, 0);
  }

#pragma unroll
  for (int vf = 0; vf < 4; ++vf) {
    const int vbase = v0 + wq * 64 + vf * 16 + (lg << 2);
    f32x4 bv = *(const f32x4*)(bias + vbase);
#pragma unroll
    for (int mf = 0; mf < 4; ++mf) {
      int m = m0 + wm * 64 + mf * 16 + l15;
      int orow = ((m & 7) << 9) | (m >> 3);   // b*T + t
      f32x4 val = acc[vf][mf] + bv;
      *(f32x4*)(out + (size_t)orow * V_ + vbase) = val;
    }
  }
}

extern "C" void kernel_launch(void* const* d_in, const int* in_sizes, int n_in,
                              void* d_out, int out_size, void* d_ws, size_t ws_size,
                              hipStream_t stream) {
  const int*   x     = (const int*)d_in[0];
  const float* emb   = (const float*)d_in[1];
  const float* W_ih0 = (const float*)d_in[2];
  const float* W_hh0 = (const float*)d_in[3];
  const float* b_ih0 = (const float*)d_in[4];
  const float* b_hh0 = (const float*)d_in[5];
  const float* W_ih1 = (const float*)d_in[6];
  const float* W_hh1 = (const float*)d_in[7];
  const float* b_ih1 = (const float*)d_in[8];
  const float* b_hh1 = (const float*)d_in[9];
  const float* fc_W  = (const float*)d_in[10];
  const float* fc_b  = (const float*)d_in[11];
  float* out = (float*)d_out;

  char* ws = (char*)d_ws;
  float*          pre0 = (float*)ws;                          // 2 MB
  unsigned short* h1b  = (unsigned short*)(ws + (2u << 20));  // 1 MB
  unsigned short* fcWb = (unsigned short*)(ws + (3u << 20));  // 8 MB

  convert_w_kernel<<<1024, 256, 0, stream>>>(fc_W, fcWb, V_ * H_ / 4);
  pre_kernel<<<256, 128, 0, stream>>>(emb, x, W_ih0, b_ih0, b_hh0, pre0);
  fused_scan<<<B_, 192, 0, stream>>>(pre0, W_hh0, W_ih1, W_hh1, b_ih1, b_hh1, h1b);
  final_gemm2<<<32 * 250, 256, 0, stream>>>(fcWb, h1b, fc_b, out);
}

// Round 3
// 671.884 us; speedup vs baseline: 1.3666x; 1.3666x over previous
//
#include <hip/hip_runtime.h>
#include <hip/hip_bf16.h>

typedef __attribute__((ext_vector_type(4))) float f32x4;
typedef __attribute__((ext_vector_type(4))) int   i32x4;
typedef __attribute__((ext_vector_type(8))) short s16x8;
typedef __attribute__((ext_vector_type(4))) unsigned short u16x4;

#define T_ 512
#define B_ 8
#define H_ 128
#define V_ 32000

// round-to-nearest-even f32 -> bf16
__device__ __forceinline__ unsigned short f2b(float f) {
  unsigned int u = __float_as_uint(f);
  u = (u + 0x7FFFu + ((u >> 16) & 1u)) >> 16;
  return (unsigned short)u;
}

__device__ __forceinline__ float tanh_fast(float x) {
  float e = __expf(2.f * x);
  return 1.f - 2.f * __builtin_amdgcn_rcpf(e + 1.f);
}

__device__ __forceinline__ float hsum4(f32x4 v) { return (v.x + v.y) + (v.z + v.w); }

__device__ __forceinline__ f32x4 shflx4(f32x4 v, int m) {
  f32x4 r;
  r.x = __shfl_xor(v.x, m, 64);
  r.y = __shfl_xor(v.y, m, 64);
  r.z = __shfl_xor(v.z, m, 64);
  r.w = __shfl_xor(v.w, m, 64);
  return r;
}

// barrier that does NOT drain vmcnt: LDS-only visibility (lgkmcnt) + s_barrier.
// All per-region cross-wave communication is through LDS; global loads (pre0
// prefetch) and stores (h1b) are thread-private, so vmcnt may stay in flight.
__device__ __forceinline__ void lds_barrier() {
  asm volatile("s_waitcnt lgkmcnt(0)\n\ts_barrier" ::: "memory");
}

// ---------------- fc_W f32 -> bf16 ----------------
__global__ __launch_bounds__(256) void convert_w_kernel(const float* __restrict__ src,
                                                        unsigned short* __restrict__ dst, int n4) {
  int idx = blockIdx.x * 256 + threadIdx.x;
  int stride = gridDim.x * 256;
  for (int c = idx; c < n4; c += stride) {
    f32x4 v = ((const f32x4*)src)[c];
    u16x4 o;
    o.x = f2b(v.x); o.y = f2b(v.y); o.z = f2b(v.z); o.w = f2b(v.w);
    ((u16x4*)dst)[c] = o;
  }
}

// ---------------- pre0 = emb[x] @ W_ih0^T + b_ih0 + b_hh0 ----------------
__global__ __launch_bounds__(128) void pre_kernel(const float* __restrict__ emb,
                                                  const int* __restrict__ x,
                                                  const float* __restrict__ W,
                                                  const float* __restrict__ b1,
                                                  const float* __restrict__ b2,
                                                  float* __restrict__ out) {
  const int tid = threadIdx.x;
  __shared__ alignas(16) float lds_in[H_];
  f32x4 w[32];
#pragma unroll
  for (int r = 0; r < 32; ++r) w[r] = *(const f32x4*)(W + tid * H_ + 4 * r);
  const float bsum = b1[tid] + b2[tid];
  const int m0 = blockIdx.x * 16;

  auto src_row = [&](int m) -> const float* {
    int t = m >> 3, b = m & 7;
    int tok = x[(b << 9) + t];          // x is [B,T]
    return emb + (size_t)tok * H_;
  };

  float stage = src_row(m0)[tid];
  for (int rr = 0; rr < 16; ++rr) {
    const int m = m0 + rr;
    lds_in[tid] = stage;
    __syncthreads();
    if (rr + 1 < 16) stage = src_row(m0 + rr + 1)[tid];
    f32x4 acc4 = {0.f, 0.f, 0.f, 0.f};
#pragma unroll
    for (int r = 0; r < 32; ++r) {
      f32x4 hv = *(const f32x4*)(lds_in + 4 * r);
      acc4 = __builtin_elementwise_fma(hv, w[r], acc4);
    }
    out[m * H_ + tid] = hsum4(acc4) + bsum;
    __syncthreads();
  }
}

// ---------------- fused dual-layer scan, v2 ----------------
// One block per batch, 6 waves = 3 pairs, ONE matrix per pair:
//   pair 0 (waves 0-1): h0[s]    = tanh(pre0[s] + W_hh0·h0[s-1])      s in [0,511]
//   pair 1 (waves 2-3): pih[s-1] = W_ih1·h0[s-1] + b_ih1 + b_hh1      s in [1,512]
//   pair 2 (waves 4-5): h1[s-2]  = tanh(pih[s-2] + W_hh1·h1[s-3])     s in [2,513]
// Thread (within pair): wave wv, lane = q*16+c; owns units u=wv*64+c*4..+3,
// K-slice = interleaved 16B granules {r*16+q*4} (disjoint banks across q).
// Weights: 4 rows x 8 f32x4 = 128 VGPR. Reduce over q: shfl_xor 16,32.
// One lds_barrier per region; pre0 prefetch depth 2 stays in flight across it.
__global__ __launch_bounds__(384, 2) void fused_scan2(
    const float* __restrict__ pre0,
    const float* __restrict__ W_hh0,
    const float* __restrict__ W_ih1,
    const float* __restrict__ W_hh1,
    const float* __restrict__ b_ih1,
    const float* __restrict__ b_hh1,
    unsigned short* __restrict__ h1b) {
  const int b    = blockIdx.x;
  const int tid  = threadIdx.x;
  const int pair = tid >> 7;
  const int p    = tid & 127;
  const int wv   = p >> 6;
  const int lane = p & 63;
  const int q    = lane >> 4;
  const int c    = lane & 15;
  const int u    = wv * 64 + c * 4;

  __shared__ alignas(16) float h0_lds[2][H_];
  __shared__ alignas(16) float pih_lds[2][H_];
  __shared__ alignas(16) float h1_lds[2][H_];

  if (tid < H_) {
    h0_lds[0][tid] = 0.f;  h0_lds[1][tid] = 0.f;
    pih_lds[0][tid] = 0.f; pih_lds[1][tid] = 0.f;
    h1_lds[0][tid] = 0.f;  h1_lds[1][tid] = 0.f;
  }

  const float* Wm = (pair == 0) ? W_hh0 : (pair == 1) ? W_ih1 : W_hh1;
  f32x4 w0[8], w1[8], w2[8], w3[8];
#pragma unroll
  for (int r = 0; r < 8; ++r) {
    w0[r] = *(const f32x4*)(Wm + (u + 0) * H_ + r * 16 + q * 4);
    w1[r] = *(const f32x4*)(Wm + (u + 1) * H_ + r * 16 + q * 4);
    w2[r] = *(const f32x4*)(Wm + (u + 2) * H_ + r * 16 + q * 4);
    w3[r] = *(const f32x4*)(Wm + (u + 3) * H_ + r * 16 + q * 4);
  }

  f32x4 bias4 = {0.f, 0.f, 0.f, 0.f};
  if (pair == 1) bias4 = *(const f32x4*)(b_ih1 + u) + *(const f32x4*)(b_hh1 + u);

  f32x4 preA = {0.f, 0.f, 0.f, 0.f}, preB = {0.f, 0.f, 0.f, 0.f};
  if (pair == 0) {
    preA = *(const f32x4*)(pre0 + (0 * B_ + b) * H_ + u);
    preB = *(const f32x4*)(pre0 + (1 * B_ + b) * H_ + u);
  }
  __syncthreads();

  auto region = [&](int s, f32x4& prec) {
    const int rd = (s + 1) & 1, wr = s & 1;
    const float* hsrc = (pair == 2) ? h1_lds[rd] : h0_lds[rd];
    f32x4 a0 = {0,0,0,0}, a1 = {0,0,0,0}, a2 = {0,0,0,0}, a3 = {0,0,0,0};
#pragma unroll
    for (int r = 0; r < 8; ++r) {
      f32x4 hv = *(const f32x4*)(hsrc + r * 16 + q * 4);
      a0 = __builtin_elementwise_fma(hv, w0[r], a0);
      a1 = __builtin_elementwise_fma(hv, w1[r], a1);
      a2 = __builtin_elementwise_fma(hv, w2[r], a2);
      a3 = __builtin_elementwise_fma(hv, w3[r], a3);
    }
    f32x4 pihv = {0, 0, 0, 0};
    if (pair == 2) pihv = *(const f32x4*)(&pih_lds[wr][u]);
    f32x4 t = { hsum4(a0), hsum4(a1), hsum4(a2), hsum4(a3) };
    t += shflx4(t, 16);
    t += shflx4(t, 32);
    if (q == 0) {
      if (pair == 0) {
        if (s < T_) {
          f32x4 val = t + prec;
          f32x4 h = { tanh_fast(val.x), tanh_fast(val.y), tanh_fast(val.z), tanh_fast(val.w) };
          *(f32x4*)(&h0_lds[wr][u]) = h;
        }
      } else if (pair == 1) {
        if (s >= 1 && s <= T_) *(f32x4*)(&pih_lds[rd][u]) = t + bias4;   // pih[s-1]
      } else {
        if (s >= 2) {
          f32x4 val = t + pihv;
          f32x4 h = { tanh_fast(val.x), tanh_fast(val.y), tanh_fast(val.z), tanh_fast(val.w) };
          *(f32x4*)(&h1_lds[wr][u]) = h;
          const int tt = s - 2;
          u16x4 o = { f2b(h.x), f2b(h.y), f2b(h.z), f2b(h.w) };
          *(u16x4*)(h1b + ((tt * B_ + b) << 7) + u) = o;
        }
      }
    }
    if (pair == 0) {                       // depth-2 prefetch: reload AFTER use
      int sn = s + 2; if (sn > T_ - 1) sn = T_ - 1;
      prec = *(const f32x4*)(pre0 + (sn * B_ + b) * H_ + u);
    }
    lds_barrier();
  };

  for (int s = 0; s < T_ + 2; s += 2) {
    region(s, preA);
    region(s + 1, preB);
  }
}

// ---------------- logits = h1 @ fc_W^T + fc_b  (bf16 MFMA) ----------------
__device__ __forceinline__ int swz(int row, int cc) {
  return row * 256 + ((cc ^ (row & 7)) << 4);
}

__global__ __launch_bounds__(256) void final_gemm2(const unsigned short* __restrict__ fcWb,
                                                   const unsigned short* __restrict__ h1b,
                                                   const float* __restrict__ bias,
                                                   float* __restrict__ out) {
  __shared__ alignas(16) char smem[32768];
  const int tid = threadIdx.x;
  const int bid = blockIdx.x;
  const int mt = bid & 31, nt = bid >> 5;   // consecutive bids share the fcW tile
  const int m0 = mt << 7, v0 = nt << 7;
  const int lane = tid & 63, wvv = tid >> 6;
  const int wm = wvv & 1, wq = wvv >> 1;

  const char* gW = (const char*)fcWb + (size_t)v0 * 256;
#pragma unroll
  for (int it = 0; it < 8; ++it) {
    int cidx = it * 256 + tid;
    i32x4 vw = *(const i32x4*)(gW + cidx * 16);
    *(i32x4*)(smem + swz(cidx >> 4, cidx & 15)) = vw;
  }
  __syncthreads();

  const int l15 = lane & 15, lg = lane >> 4;
  f32x4 acc[4][4] = {};   // [vf][mf]
#pragma unroll
  for (int kk = 0; kk < 4; ++kk) {
    const int cc = kk * 4 + lg;
    s16x8 a[4], bfr[4];
#pragma unroll
    for (int vf = 0; vf < 4; ++vf) {
      int row = wq * 64 + vf * 16 + l15;
      a[vf] = *(const s16x8*)(smem + swz(row, cc));
    }
#pragma unroll
    for (int mf = 0; mf < 4; ++mf) {
      int mr = m0 + wm * 64 + mf * 16 + l15;
      bfr[mf] = *(const s16x8*)(h1b + mr * H_ + kk * 32 + lg * 8);
    }
#pragma unroll
    for (int vf = 0; vf < 4; ++vf)
#pragma unroll
      for (int mf = 0; mf < 4; ++mf)
        acc[vf][mf] = __builtin_amdgcn_mfma_f32_16x16x32_bf16(a[vf], bfr[mf], acc[vf][mf], 0, 0, 0);
  }

#pragma unroll
  for (int vf = 0; vf < 4; ++vf) {
    const int vbase = v0 + wq * 64 + vf * 16 + (lg << 2);
    f32x4 bv = *(const f32x4*)(bias + vbase);
#pragma unroll
    for (int mf = 0; mf < 4; ++mf) {
      int m = m0 + wm * 64 + mf * 16 + l15;
      int orow = ((m & 7) << 9) | (m >> 3);   // b*T + t
      f32x4 val = acc[vf][mf] + bv;
      *(f32x4*)(out + (size_t)orow * V_ + vbase) = val;
    }
  }
}

extern "C" void kernel_launch(void* const* d_in, const int* in_sizes, int n_in,
                              void* d_out, int out_size, void* d_ws, size_t ws_size,
                              hipStream_t stream) {
  const int*   x     = (const int*)d_in[0];
  const float* emb   = (const float*)d_in[1];
  const float* W_ih0 = (const float*)d_in[2];
  const float* W_hh0 = (const float*)d_in[3];
  const float* b_ih0 = (const float*)d_in[4];
  const float* b_hh0 = (const float*)d_in[5];
  const float* W_ih1 = (const float*)d_in[6];
  const float* W_hh1 = (const float*)d_in[7];
  const float* b_ih1 = (const float*)d_in[8];
  const float* b_hh1 = (const float*)d_in[9];
  const float* fc_W  = (const float*)d_in[10];
  const float* fc_b  = (const float*)d_in[11];
  float* out = (float*)d_out;

  char* ws = (char*)d_ws;
  float*          pre0 = (float*)ws;                          // 2 MB
  unsigned short* h1b  = (unsigned short*)(ws + (2u << 20));  // 1 MB
  unsigned short* fcWb = (unsigned short*)(ws + (3u << 20));  // 8 MB

  convert_w_kernel<<<1024, 256, 0, stream>>>(fc_W, fcWb, V_ * H_ / 4);
  pre_kernel<<<256, 128, 0, stream>>>(emb, x, W_ih0, b_ih0, b_hh0, pre0);
  fused_scan2<<<B_, 384, 0, stream>>>(pre0, W_hh0, W_ih1, W_hh1, b_ih1, b_hh1, h1b);
  final_gemm2<<<32 * 250, 256, 0, stream>>>(fcWb, h1b, fc_b, out);
}

// Round 4
// 548.285 us; speedup vs baseline: 1.6747x; 1.2254x over previous
//
#include <hip/hip_runtime.h>
#include <hip/hip_bf16.h>

typedef __attribute__((ext_vector_type(4))) float f32x4;
typedef __attribute__((ext_vector_type(4))) int   i32x4;
typedef __attribute__((ext_vector_type(8))) short s16x8;
typedef __attribute__((ext_vector_type(4))) unsigned short u16x4;

#define T_ 512
#define B_ 8
#define H_ 128
#define V_ 32000

// round-to-nearest-even f32 -> bf16
__device__ __forceinline__ unsigned short f2b(float f) {
  unsigned int u = __float_as_uint(f);
  u = (u + 0x7FFFu + ((u >> 16) & 1u)) >> 16;
  return (unsigned short)u;
}

__device__ __forceinline__ float tanh_fast(float x) {
  float e = __expf(2.f * x);
  return 1.f - 2.f * __builtin_amdgcn_rcpf(e + 1.f);
}

__device__ __forceinline__ float hsum4(f32x4 v) { return (v.x + v.y) + (v.z + v.w); }

// Sum over the 4 q-groups (16-lane rows) of a wave, result in all lanes.
// Stage 1: v_permlane16_swap(a,b) with a=b=x: a'=[r0,r0,r2,r2], b'=[r1,r1,r3,r3]
//   -> a'+b' = row-pair sums. Stage 2: v_permlane32_swap: half-swap -> full sum.
// Pure VALU (no LDS pipe), ~25cy chain vs ~240cy for ds-based shfl_xor.
__device__ __forceinline__ float qsum(float x) {
  float a, b;
  asm volatile("v_mov_b32 %0, %2\n\t"
               "v_mov_b32 %1, %2\n\t"
               "v_permlane16_swap_b32 %0, %1"
               : "=&v"(a), "=&v"(b) : "v"(x));
  float s = a + b;
  float c, d;
  asm volatile("v_mov_b32 %0, %2\n\t"
               "v_mov_b32 %1, %2\n\t"
               "v_permlane32_swap_b32 %0, %1"
               : "=&v"(c), "=&v"(d) : "v"(s));
  return c + d;
}

// barrier that does NOT drain vmcnt: LDS-only visibility + s_barrier.
__device__ __forceinline__ void lds_barrier() {
  asm volatile("s_waitcnt lgkmcnt(0)\n\ts_barrier" ::: "memory");
}

// ---------------- fc_W f32 -> bf16 ----------------
__global__ __launch_bounds__(256) void convert_w_kernel(const float* __restrict__ src,
                                                        unsigned short* __restrict__ dst, int n4) {
  int idx = blockIdx.x * 256 + threadIdx.x;
  int stride = gridDim.x * 256;
  for (int c = idx; c < n4; c += stride) {
    f32x4 v = ((const f32x4*)src)[c];
    u16x4 o;
    o.x = f2b(v.x); o.y = f2b(v.y); o.z = f2b(v.z); o.w = f2b(v.w);
    ((u16x4*)dst)[c] = o;
  }
}

// ---------------- pre0 = emb[x] @ W_ih0^T + b_ih0 + b_hh0 ----------------
__global__ __launch_bounds__(128) void pre_kernel(const float* __restrict__ emb,
                                                  const int* __restrict__ x,
                                                  const float* __restrict__ W,
                                                  const float* __restrict__ b1,
                                                  const float* __restrict__ b2,
                                                  float* __restrict__ out) {
  const int tid = threadIdx.x;
  __shared__ alignas(16) float lds_in[H_];
  f32x4 w[32];
#pragma unroll
  for (int r = 0; r < 32; ++r) w[r] = *(const f32x4*)(W + tid * H_ + 4 * r);
  const float bsum = b1[tid] + b2[tid];
  const int m0 = blockIdx.x * 16;

  auto src_row = [&](int m) -> const float* {
    int t = m >> 3, b = m & 7;
    int tok = x[(b << 9) + t];          // x is [B,T]
    return emb + (size_t)tok * H_;
  };

  float stage = src_row(m0)[tid];
  for (int rr = 0; rr < 16; ++rr) {
    const int m = m0 + rr;
    lds_in[tid] = stage;
    __syncthreads();
    if (rr + 1 < 16) stage = src_row(m0 + rr + 1)[tid];
    f32x4 acc4 = {0.f, 0.f, 0.f, 0.f};
#pragma unroll
    for (int r = 0; r < 32; ++r) {
      f32x4 hv = *(const f32x4*)(lds_in + 4 * r);
      acc4 = __builtin_elementwise_fma(hv, w[r], acc4);
    }
    out[m * H_ + tid] = hsum4(acc4) + bsum;
    __syncthreads();
  }
}

// ---------------- fused dual-layer scan, v3 ----------------
// One block per batch, 6 waves = 3 pairs, ONE matrix per pair (see round-3 notes).
// v3: permlane butterfly reduce (no LDS-pipe shuffles), amdgpu_waves_per_eu(2,2)
// so the 128 weight VGPRs stay resident (allocator targets exactly 2 waves/EU).
#define DO_REGION(S, RD, WR, PREC)                                              \
  {                                                                             \
    const int s_ = (S);                                                         \
    if (pair == 0) {                                                            \
      const float* hsrc = h0_lds[RD];                                           \
      f32x4 a0 = {0,0,0,0}, a1 = {0,0,0,0}, a2 = {0,0,0,0}, a3 = {0,0,0,0};     \
      _Pragma("unroll")                                                         \
      for (int r = 0; r < 8; ++r) {                                             \
        f32x4 hv = *(const f32x4*)(hsrc + r * 16 + q * 4);                      \
        a0 = __builtin_elementwise_fma(hv, w0[r], a0);                          \
        a1 = __builtin_elementwise_fma(hv, w1[r], a1);                          \
        a2 = __builtin_elementwise_fma(hv, w2[r], a2);                          \
        a3 = __builtin_elementwise_fma(hv, w3[r], a3);                          \
      }                                                                         \
      f32x4 t;                                                                  \
      t.x = qsum(hsum4(a0)); t.y = qsum(hsum4(a1));                             \
      t.z = qsum(hsum4(a2)); t.w = qsum(hsum4(a3));                             \
      if (s_ < T_) {                                                            \
        f32x4 val = t + (PREC);                                                 \
        f32x4 h = { tanh_fast(val.x), tanh_fast(val.y),                         \
                    tanh_fast(val.z), tanh_fast(val.w) };                       \
        if (q == 0) *(f32x4*)(&h0_lds[WR][u]) = h;                              \
      }                                                                         \
      int sn = s_ + 2; if (sn > T_ - 1) sn = T_ - 1;                            \
      (PREC) = *(const f32x4*)(pre0 + (sn * B_ + b) * H_ + u);                  \
    } else if (pair == 1) {                                                     \
      const float* hsrc = h0_lds[RD];                                           \
      f32x4 a0 = {0,0,0,0}, a1 = {0,0,0,0}, a2 = {0,0,0,0}, a3 = {0,0,0,0};     \
      _Pragma("unroll")                                                         \
      for (int r = 0; r < 8; ++r) {                                             \
        f32x4 hv = *(const f32x4*)(hsrc + r * 16 + q * 4);                      \
        a0 = __builtin_elementwise_fma(hv, w0[r], a0);                          \
        a1 = __builtin_elementwise_fma(hv, w1[r], a1);                          \
        a2 = __builtin_elementwise_fma(hv, w2[r], a2);                          \
        a3 = __builtin_elementwise_fma(hv, w3[r], a3);                          \
      }                                                                         \
      f32x4 t;                                                                  \
      t.x = qsum(hsum4(a0)); t.y = qsum(hsum4(a1));                             \
      t.z = qsum(hsum4(a2)); t.w = qsum(hsum4(a3));                             \
      if (s_ >= 1 && s_ <= T_ && q == 0)                                        \
        *(f32x4*)(&pih_lds[RD][u]) = t + bias4;                                 \
    } else if (s_ >= 2) {                                                       \
      f32x4 pihv = *(const f32x4*)(&pih_lds[WR][u]);                            \
      const float* hsrc = h1_lds[RD];                                           \
      f32x4 a0 = {0,0,0,0}, a1 = {0,0,0,0}, a2 = {0,0,0,0}, a3 = {0,0,0,0};     \
      _Pragma("unroll")                                                         \
      for (int r = 0; r < 8; ++r) {                                             \
        f32x4 hv = *(const f32x4*)(hsrc + r * 16 + q * 4);                      \
        a0 = __builtin_elementwise_fma(hv, w0[r], a0);                          \
        a1 = __builtin_elementwise_fma(hv, w1[r], a1);                          \
        a2 = __builtin_elementwise_fma(hv, w2[r], a2);                          \
        a3 = __builtin_elementwise_fma(hv, w3[r], a3);                          \
      }                                                                         \
      f32x4 t;                                                                  \
      t.x = qsum(hsum4(a0)); t.y = qsum(hsum4(a1));                             \
      t.z = qsum(hsum4(a2)); t.w = qsum(hsum4(a3));                             \
      f32x4 val = t + pihv;                                                     \
      f32x4 h = { tanh_fast(val.x), tanh_fast(val.y),                           \
                  tanh_fast(val.z), tanh_fast(val.w) };                         \
      if (q == 0) {                                                             \
        *(f32x4*)(&h1_lds[WR][u]) = h;                                          \
        const int tt = s_ - 2;                                                  \
        u16x4 o = { f2b(h.x), f2b(h.y), f2b(h.z), f2b(h.w) };                   \
        *(u16x4*)(h1b + ((tt * B_ + b) << 7) + u) = o;                          \
      }                                                                         \
    }                                                                           \
    lds_barrier();                                                              \
  }

__global__ __launch_bounds__(384) __attribute__((amdgpu_waves_per_eu(2, 2)))
void fused_scan3(const float* __restrict__ pre0,
                 const float* __restrict__ W_hh0,
                 const float* __restrict__ W_ih1,
                 const float* __restrict__ W_hh1,
                 const float* __restrict__ b_ih1,
                 const float* __restrict__ b_hh1,
                 unsigned short* __restrict__ h1b) {
  const int b    = blockIdx.x;
  const int tid  = threadIdx.x;
  const int pair = tid >> 7;
  const int p    = tid & 127;
  const int wv   = p >> 6;
  const int lane = p & 63;
  const int q    = lane >> 4;
  const int c    = lane & 15;
  const int u    = wv * 64 + c * 4;

  __shared__ alignas(16) float h0_lds[2][H_];
  __shared__ alignas(16) float pih_lds[2][H_];
  __shared__ alignas(16) float h1_lds[2][H_];

  if (tid < H_) {
    h0_lds[0][tid] = 0.f;  h0_lds[1][tid] = 0.f;
    pih_lds[0][tid] = 0.f; pih_lds[1][tid] = 0.f;
    h1_lds[0][tid] = 0.f;  h1_lds[1][tid] = 0.f;
  }

  const float* Wm = (pair == 0) ? W_hh0 : (pair == 1) ? W_ih1 : W_hh1;
  f32x4 w0[8], w1[8], w2[8], w3[8];
#pragma unroll
  for (int r = 0; r < 8; ++r) {
    w0[r] = *(const f32x4*)(Wm + (u + 0) * H_ + r * 16 + q * 4);
    w1[r] = *(const f32x4*)(Wm + (u + 1) * H_ + r * 16 + q * 4);
    w2[r] = *(const f32x4*)(Wm + (u + 2) * H_ + r * 16 + q * 4);
    w3[r] = *(const f32x4*)(Wm + (u + 3) * H_ + r * 16 + q * 4);
  }

  f32x4 bias4 = {0.f, 0.f, 0.f, 0.f};
  if (pair == 1) bias4 = *(const f32x4*)(b_ih1 + u) + *(const f32x4*)(b_hh1 + u);

  f32x4 preA = {0.f, 0.f, 0.f, 0.f}, preB = {0.f, 0.f, 0.f, 0.f};
  if (pair == 0) {
    preA = *(const f32x4*)(pre0 + (0 * B_ + b) * H_ + u);
    preB = *(const f32x4*)(pre0 + (1 * B_ + b) * H_ + u);
  }
  __syncthreads();

  for (int s2 = 0; s2 < T_ + 2; s2 += 2) {
    DO_REGION(s2,     1, 0, preA)   // even region: read buf 1, write buf 0
    DO_REGION(s2 + 1, 0, 1, preB)   // odd  region: read buf 0, write buf 1
  }
}

// ---------------- logits = h1 @ fc_W^T + fc_b  (bf16 MFMA, v3) ----------------
// m-tile = 128 consecutive t of ONE batch -> block writes 128 CONSECUTIVE out rows.
// Each wave owns 32 rows x the FULL 128-v span -> every 128B line written by one
// wave in adjacent iterations (no cross-wave half-lines). Grid is v-inner so
// concurrent blocks tile a contiguous 16MB output span.
__device__ __forceinline__ int swz(int row, int cc) {
  return row * 256 + ((cc ^ (row & 7)) << 4);
}

__global__ __launch_bounds__(256) void final_gemm3(const unsigned short* __restrict__ fcWb,
                                                   const unsigned short* __restrict__ h1b,
                                                   const float* __restrict__ bias,
                                                   float* __restrict__ out) {
  __shared__ alignas(16) char smem[32768];
  const int tid = threadIdx.x;
  const int bid = blockIdx.x;
  const int mt = bid / 250, nt = bid - mt * 250;   // v-inner order
  const int bb = mt >> 2, tb = mt & 3;
  const int t0 = tb << 7;
  const int v0 = nt << 7;
  const int lane = tid & 63, wvv = tid >> 6;       // wvv: 32-row block

  // stage fcW tile (32KB) with swizzle
  const char* gW = (const char*)fcWb + (size_t)v0 * 256;
#pragma unroll
  for (int it = 0; it < 8; ++it) {
    int cidx = it * 256 + tid;
    i32x4 vw = *(const i32x4*)(gW + cidx * 16);
    *(i32x4*)(smem + swz(cidx >> 4, cidx & 15)) = vw;
  }
  __syncthreads();

  const int l15 = lane & 15, lg = lane >> 4;
  f32x4 acc[8][2] = {};   // [vf][mf]
#pragma unroll
  for (int kk = 0; kk < 4; ++kk) {
    const int cc = kk * 4 + lg;
    s16x8 a[8], bfr[2];
#pragma unroll
    for (int vf = 0; vf < 8; ++vf)
      a[vf] = *(const s16x8*)(smem + swz(vf * 16 + l15, cc));
#pragma unroll
    for (int mf = 0; mf < 2; ++mf) {
      int trow = t0 + wvv * 32 + mf * 16 + l15;
      bfr[mf] = *(const s16x8*)(h1b + (size_t)((trow << 3) + bb) * H_ + kk * 32 + lg * 8);
    }
#pragma unroll
    for (int vf = 0; vf < 8; ++vf)
#pragma unroll
      for (int mf = 0; mf < 2; ++mf)
        acc[vf][mf] = __builtin_amdgcn_mfma_f32_16x16x32_bf16(a[vf], bfr[mf], acc[vf][mf], 0, 0, 0);
  }

  f32x4 bv[8];
#pragma unroll
  for (int vf = 0; vf < 8; ++vf)
    bv[vf] = *(const f32x4*)(bias + v0 + vf * 16 + (lg << 2));

#pragma unroll
  for (int mf = 0; mf < 2; ++mf) {
    const int trow = t0 + wvv * 32 + mf * 16 + l15;
    const size_t rowoff = (size_t)((bb << 9) + trow) * V_;
#pragma unroll
    for (int vf = 0; vf < 8; ++vf) {
      const int v = v0 + vf * 16 + (lg << 2);
      *(f32x4*)(out + rowoff + v) = acc[vf][mf] + bv[vf];
    }
  }
}

extern "C" void kernel_launch(void* const* d_in, const int* in_sizes, int n_in,
                              void* d_out, int out_size, void* d_ws, size_t ws_size,
                              hipStream_t stream) {
  const int*   x     = (const int*)d_in[0];
  const float* emb   = (const float*)d_in[1];
  const float* W_ih0 = (const float*)d_in[2];
  const float* W_hh0 = (const float*)d_in[3];
  const float* b_ih0 = (const float*)d_in[4];
  const float* b_hh0 = (const float*)d_in[5];
  const float* W_ih1 = (const float*)d_in[6];
  const float* W_hh1 = (const float*)d_in[7];
  const float* b_ih1 = (const float*)d_in[8];
  const float* b_hh1 = (const float*)d_in[9];
  const float* fc_W  = (const float*)d_in[10];
  const float* fc_b  = (const float*)d_in[11];
  float* out = (float*)d_out;

  char* ws = (char*)d_ws;
  float*          pre0 = (float*)ws;                          // 2 MB
  unsigned short* h1b  = (unsigned short*)(ws + (2u << 20));  // 1 MB
  unsigned short* fcWb = (unsigned short*)(ws + (3u << 20));  // 8 MB

  convert_w_kernel<<<1024, 256, 0, stream>>>(fc_W, fcWb, V_ * H_ / 4);
  pre_kernel<<<256, 128, 0, stream>>>(emb, x, W_ih0, b_ih0, b_hh0, pre0);
  fused_scan3<<<B_, 384, 0, stream>>>(pre0, W_hh0, W_ih1, W_hh1, b_ih1, b_hh1, h1b);
  final_gemm3<<<32 * 250, 256, 0, stream>>>(fcWb, h1b, fc_b, out);
}